// Round 12
// baseline (141.383 us; speedup 1.0000x reference)
//
#include <hip/hip_runtime.h>

// Problem constants (from reference)
#define GATE_SLOPE 10.0f
#define ALPHA 0.8f
constexpr int B_ = 256, IN_DIM = 128, OUT_DIM = 128, NB = 16;

__device__ __forceinline__ float rcpf(float x)  { return __builtin_amdgcn_rcpf(x); }
__device__ __forceinline__ float ex2f(float x)  { return __builtin_amdgcn_exp2f(x); }

// Wave-uniform register broadcast: lane j's copy of x, delivered via SGPR.
// Replaces per-step LDS reads (ds_read ~120cy latency, m117) with a VALU-pipe
// readlane (no memory latency, no lgkmcnt).
__device__ __forceinline__ float rdlane(float x, int j) {
    return __builtin_bit_cast(float,
        __builtin_amdgcn_readlane(__builtin_bit_cast(int, x), j));
}

// DPP cross-lane add: v + perm(v). Masks {1,2,7,15} (GF(2)-independent) give
// the full 16-lane sum in every lane on the VALU pipe.
template<int CTRL>
__device__ __forceinline__ float dpp_add(float v) {
    int s = __builtin_amdgcn_update_dpp(0, __builtin_bit_cast(int, v),
                                        CTRL, 0xF, 0xF, true);
    return v + __builtin_bit_cast(float, s);
}

// Block: 256 threads = 16 o x 16 n for one fixed i. Grid: 128 i * 8 o-groups.
// Atomics spread over R replicas of the 32K-float output (replica = i & repmask).
//
// Math (exact algebraic folds of the reference):
//  sigmoid(10z) = rcp(1+exp2(-z*S)), S = 10*log2(e)
//  e1 = exp2((ec-xs)S) = E1c * wb,  E1c = exp2(ec*S) [per-thread],
//                                   wb  = exp2(-xs*S) [per-b]
//  cp = 1/(1+e1); cn = e1/(e1+E2c), E2c = exp2(2*ec*S)
//  bs' = A*bs + c,  A = 1-(su2+sl2), c = su2-sl2,
//        su2 = 0.2*up*cp, sl2 = 0.2*(1-up)*cn
//  v = basis*cf = fma(-2*ps*cf, r3, ps*cf+bi*cf), r3 = rcp(1+exp2(kt*z)),
//        kt = 2*kk*log2(e), z = xs+ec*bs
// Ranges (fixed inputs): ec in [0.5,2.5], |xs| <= ~4.7 -> all finite fp32.
//
// Data plumbing: the 256-row {xs,upA,upB,wb} table is staged once to LDS,
// then pulled into 16 wave-private VGPRs/lane (lane l holds rows l, 64+l,
// 128+l, 192+l). The b-loop fetches scalars with readlane (wave-uniform j)
// — the inner loop touches NO memory except the output atomics.
__launch_bounds__(256, 4)
__global__ void ferro_kernel(const float* __restrict__ x,
                             const float* __restrict__ k,
                             const float* __restrict__ Ec,
                             const float* __restrict__ Ps,
                             const float* __restrict__ bias,
                             const float* __restrict__ coef,
                             float* __restrict__ target,
                             int repmask)
{
    constexpr float LOG2E = 1.4426950408889634f;
    constexpr float S = GATE_SLOPE * LOG2E;

    __shared__ float4 st[B_];   // {xs, upA=0.2*up, upB=0.2*(1-up), wb=exp2(-xs*S)}

    const int t   = threadIdx.x;
    const int blk = blockIdx.x;
    const int i      = blk >> 3;          // 128 i's
    const int o_base = (blk & 7) << 4;    // 8 groups of 16 o's

    {
        float xb = x[t * IN_DIM + i];
        float xp = (t == 0) ? 0.0f : x[(t - 1) * IN_DIM + i];
        float up = rcpf(1.0f + ex2f((xp - xb) * S));   // sigmoid(10*(xb-xp))
        float upA = 0.2f * up;
        st[t] = make_float4(xb, upA, 0.2f - upA, ex2f(-xb * S));
    }
    __syncthreads();

    // Pull the whole table into wave-private registers: 4 float4 per lane.
    const int lane = t & 63;
    const float4 q0 = st[lane];
    const float4 q1 = st[64 + lane];
    const float4 q2 = st[128 + lane];
    const float4 q3 = st[192 + lane];

    const long pidx = (long)i * (OUT_DIM * NB) + (long)o_base * NB + t;
    const float kk = k[pidx];
    const float ec = Ec[pidx];
    const float ps = Ps[pidx];
    const float bi = bias[pidx];
    const float cf = coef[pidx];

    const int o = o_base + (t >> 4);
    const int n = t & 15;

    // Per-thread precomputed constants.
    const float ecS   = ec * S;
    const float E1c   = ex2f(ecS);                 // e1 = E1c * wb
    const float E2c   = ex2f(2.0f * ecS);
    const float kt    = kk * (2.0f * LOG2E);
    const float ktec  = kt * ec;
    const float psc   = ps * cf;
    const float m2psc = -2.0f * psc;
    const float pbc   = __builtin_fmaf(bi, cf, psc);   // ps*cf + bi*cf

    float* __restrict__ rbase = target + ((long)(i & repmask) << 15);

    float bs = 1.0f;

    // 64 steps per register-quad; 8-step chunks with phase-split ILP.
    auto run64 = [&](const float4 rc, const int cbase) {
        for (int jj = 0; jj < 64; jj += 8) {
            // Phase A: bs-independent gate algebra (8 independent iters,
            // operands broadcast from registers via readlane — no memory).
            float AA[8], CC[8], KX[8];
            #pragma unroll
            for (int u = 0; u < 8; ++u) {
                const int j = jj + u;
                const float wb  = rdlane(rc.w, j);
                const float e1  = E1c * wb;                  // exp2((ec-xs)*S)
                const float ra  = rcpf(1.0f + e1);           // cp
                const float rb  = rcpf(e1 + E2c);
                const float su2 = rdlane(rc.y, j) * ra;      // 0.2*up*cp
                const float sl2 = (rdlane(rc.z, j) * e1) * rb; // 0.2*(1-up)*cn
                AA[u] = 1.0f - (su2 + sl2);                  // A
                CC[u] = su2 - sl2;                           // c
                KX[u] = kt * rdlane(rc.x, j);
            }
            // Phase B1: the only true serial chain — 8 dependent fmas.
            float ZK[8];
            #pragma unroll
            for (int u = 0; u < 8; ++u) {
                bs = __builtin_fmaf(AA[u], bs, CC[u]);        // bs' = A*bs + c
                ZK[u] = __builtin_fmaf(ktec, bs, KX[u]);      // kt*(xs+ec*bs)
            }
            // Phase B2: 8 independent exp2+rcp+fma.
            float VV[8];
            #pragma unroll
            for (int u = 0; u < 8; ++u)
                VV[u] = __builtin_fmaf(m2psc, rcpf(1.0f + ex2f(ZK[u])), pbc);
            // Phase B3: 8 independent 4-op DPP reduction trees.
            #pragma unroll
            for (int u = 0; u < 8; ++u) {
                float v = VV[u];
                v = dpp_add<0xB1>(v);    // xor 1
                v = dpp_add<0x4E>(v);    // xor 2
                v = dpp_add<0x141>(v);   // xor 7 (row_half_mirror)
                v = dpp_add<0x140>(v);   // xor 15 (row_mirror)
                VV[u] = v;
            }
            // Phase B4: one exec-mask region, 8 back-to-back atomics.
            if (n == 0) {
                #pragma unroll
                for (int u = 0; u < 8; ++u)
                    atomicAdd(&rbase[((cbase + jj + u) << 7) + o], VV[u]);
            }
        }
    };
    run64(q0, 0);
    run64(q1, 64);
    run64(q2, 128);
    run64(q3, 192);
}

// Stage 2: out[j] = sum over R replicas of ws[(r<<15)+j], j in [0,32768).
__global__ void reduce_kernel(const float* __restrict__ ws,
                              float* __restrict__ out, int R)
{
    const int j = blockIdx.x * blockDim.x + threadIdx.x;
    float s = 0.0f;
    for (int r = 0; r < R; ++r) s += ws[((long)r << 15) + j];
    out[j] = s;
}

extern "C" void kernel_launch(void* const* d_in, const int* in_sizes, int n_in,
                              void* d_out, int out_size, void* d_ws, size_t ws_size,
                              hipStream_t stream) {
    const float* x    = (const float*)d_in[0];
    const float* k    = (const float*)d_in[1];
    const float* Ec   = (const float*)d_in[2];
    const float* Ps   = (const float*)d_in[3];
    const float* bias = (const float*)d_in[4];
    const float* coef = (const float*)d_in[5];
    float* out = (float*)d_out;
    float* ws  = (float*)d_ws;

    const size_t repBytes = (size_t)32768 * sizeof(float);   // 128 KB per replica
    int R = 0;
    if (ws_size >= repBytes) {
        R = 1;
        while (R < 16 && (size_t)(R * 2) * repBytes <= ws_size) R <<= 1;
    }

    if (R >= 2) {
        hipMemsetAsync(ws, 0, (size_t)R * repBytes, stream);
        ferro_kernel<<<dim3(IN_DIM * 8), dim3(256), 0, stream>>>(
            x, k, Ec, Ps, bias, coef, ws, R - 1);
        reduce_kernel<<<dim3(128), dim3(256), 0, stream>>>(ws, out, R);
    } else {
        hipMemsetAsync(out, 0, (size_t)out_size * sizeof(float), stream);
        ferro_kernel<<<dim3(IN_DIM * 8), dim3(256), 0, stream>>>(
            x, k, Ec, Ps, bias, coef, out, 0);
    }
}

// Round 15
// 131.599 us; speedup vs baseline: 1.0743x; 1.0743x over previous
//
#include <hip/hip_runtime.h>

// Problem constants (from reference)
#define GATE_SLOPE 10.0f
#define ALPHA 0.8f
constexpr int B_ = 256, IN_DIM = 128, OUT_DIM = 128, NB = 16;
constexpr int BPAD = 16;   // prefetch overrun pad (benign rows)

__device__ __forceinline__ float rcpf(float x)  { return __builtin_amdgcn_rcpf(x); }
__device__ __forceinline__ float ex2f(float x)  { return __builtin_amdgcn_exp2f(x); }

// DPP cross-lane add: v + perm(v). Masks {1,2,7,15} (GF(2)-independent) give
// the full 16-lane sum in every lane on the VALU pipe.
template<int CTRL>
__device__ __forceinline__ float dpp_add(float v) {
    int s = __builtin_amdgcn_update_dpp(0, __builtin_bit_cast(int, v),
                                        CTRL, 0xF, 0xF, true);
    return v + __builtin_bit_cast(float, s);
}

// Force-materialize 8 floats in VGPRs: opaque to the optimizer, so phase
// arrays can neither be rematerialized nor sunk — this is what defeats the
// compiler's 3-rounds-running collapse of the software pipeline (VGPR=20).
#define PIN8(A) asm volatile("" : "+v"(A[0]), "+v"(A[1]), "+v"(A[2]), \
    "+v"(A[3]), "+v"(A[4]), "+v"(A[5]), "+v"(A[6]), "+v"(A[7]))

// Phase A (gates): bs-independent, 2 trans + ~10 VALU per step, 8 indep steps.
#define GATES(b0, AA, CC, KX)                                         \
    do {                                                              \
        _Pragma("unroll")                                             \
        for (int u = 0; u < 8; ++u) {                                 \
            const float4 s4 = st[(b0) + u];  /* broadcast */          \
            const float e1  = E1c * s4.w;    /* exp2((ec-xs)*S) */    \
            const float ra  = rcpf(1.0f + e1);            /* cp */    \
            const float rb  = rcpf(e1 + E2c);                         \
            const float su2 = s4.y * ra;          /* 0.2*up*cp */     \
            const float sl2 = (s4.z * e1) * rb;   /* 0.2*(1-up)*cn */ \
            AA[u] = 1.0f - (su2 + sl2);                               \
            CC[u] = su2 - sl2;                                        \
            KX[u] = kt * s4.x;                                        \
        }                                                             \
    } while (0)

// Phase B (recursion + output): serial 2-fma chain, then 8 indep trans+DPP.
#define OUTPUTS(b0, AA, CC, KX)                                       \
    do {                                                              \
        float ZK[8];                                                  \
        _Pragma("unroll")                                             \
        for (int u = 0; u < 8; ++u) {                                 \
            bs = __builtin_fmaf(AA[u], bs, CC[u]);                    \
            ZK[u] = __builtin_fmaf(ktec, bs, KX[u]);                  \
        }                                                             \
        float VV[8];                                                  \
        _Pragma("unroll")                                             \
        for (int u = 0; u < 8; ++u)                                   \
            VV[u] = __builtin_fmaf(m2psc, rcpf(1.0f + ex2f(ZK[u])), pbc); \
        _Pragma("unroll")                                             \
        for (int u = 0; u < 8; ++u) {                                 \
            float v = VV[u];                                          \
            v = dpp_add<0xB1>(v);   /* xor 1 */                       \
            v = dpp_add<0x4E>(v);   /* xor 2 */                       \
            v = dpp_add<0x141>(v);  /* xor 7 */                       \
            v = dpp_add<0x140>(v);  /* xor 15 */                      \
            VV[u] = v;                                                \
        }                                                             \
        if (n == 0) {                                                 \
            _Pragma("unroll")                                         \
            for (int u = 0; u < 8; ++u)                               \
                atomicAdd(&rbase[(((b0) + u) << 7) + o], VV[u]);      \
        }                                                             \
    } while (0)

// Block: 256 threads = 16 o x 16 n for one fixed i. Grid: 128 i * 8 o-groups.
// Atomics spread over R replicas of the 32K-float output (replica = i & repmask).
// Math: exact algebraic folds of the reference (see r11 notes); all exp2 args
// < 126 for these inputs (ec in [0.5,2.5], |xs| <= ~4.7) — everything finite.
// Structure: 2-deep software pipeline, gates(k+1) pinned via asm, so the
// scheduler interleaves the independent gate work with chunk k's serial
// recursion/output tail. VGPR count is the check (~20 = collapsed, ~80 = held).
__launch_bounds__(256, 4)
__global__ void ferro_kernel(const float* __restrict__ x,
                             const float* __restrict__ k,
                             const float* __restrict__ Ec,
                             const float* __restrict__ Ps,
                             const float* __restrict__ bias,
                             const float* __restrict__ coef,
                             float* __restrict__ target,
                             int repmask)
{
    constexpr float LOG2E = 1.4426950408889634f;
    constexpr float S = GATE_SLOPE * LOG2E;

    __shared__ float4 st[B_ + BPAD]; // {xs, upA=0.2*up, upB=0.2*(1-up), wb=exp2(-xs*S)}

    const int t   = threadIdx.x;
    const int blk = blockIdx.x;
    const int i      = blk >> 3;          // 128 i's
    const int o_base = (blk & 7) << 4;    // 8 groups of 16 o's

    {
        float xb = x[t * IN_DIM + i];
        float xp = (t == 0) ? 0.0f : x[(t - 1) * IN_DIM + i];
        float up = rcpf(1.0f + ex2f((xp - xb) * S));   // sigmoid(10*(xb-xp))
        float upA = 0.2f * up;
        st[t] = make_float4(xb, upA, 0.2f - upA, ex2f(-xb * S));
        if (t < BPAD) st[B_ + t] = make_float4(0.0f, 0.1f, 0.1f, 1.0f); // benign pad
    }
    __syncthreads();

    const long pidx = (long)i * (OUT_DIM * NB) + (long)o_base * NB + t;
    const float kk = k[pidx];
    const float ec = Ec[pidx];
    const float ps = Ps[pidx];
    const float bi = bias[pidx];
    const float cf = coef[pidx];

    const int o = o_base + (t >> 4);
    const int n = t & 15;

    // Per-thread precomputed constants.
    const float ecS   = ec * S;
    const float E1c   = ex2f(ecS);                 // e1 = E1c * wb
    const float E2c   = ex2f(2.0f * ecS);
    const float kt    = kk * (2.0f * LOG2E);
    const float ktec  = kt * ec;
    const float psc   = ps * cf;
    const float m2psc = -2.0f * psc;
    const float pbc   = __builtin_fmaf(bi, cf, psc);   // ps*cf + bi*cf

    float* __restrict__ rbase = target + ((long)(i & repmask) << 15);

    float bs = 1.0f;

    // 2-deep software pipeline over 8-step chunks (32 chunks, 2 per iter).
    float A0[8], C0[8], K0[8], A1[8], C1[8], K1[8];
    GATES(0, A0, C0, K0);  PIN8(A0); PIN8(C0); PIN8(K0);
    for (int b0 = 0; b0 < B_; b0 += 16) {
        GATES(b0 + 8, A1, C1, K1);  PIN8(A1); PIN8(C1); PIN8(K1);
        OUTPUTS(b0, A0, C0, K0);
        GATES(b0 + 16, A0, C0, K0); PIN8(A0); PIN8(C0); PIN8(K0); // pad covers b0=240
        OUTPUTS(b0 + 8, A1, C1, K1);
    }
}

// Stage 2: out[j] = sum over R replicas of ws[(r<<15)+j], j in [0,32768).
__global__ void reduce_kernel(const float* __restrict__ ws,
                              float* __restrict__ out, int R)
{
    const int j = blockIdx.x * blockDim.x + threadIdx.x;
    float s = 0.0f;
    for (int r = 0; r < R; ++r) s += ws[((long)r << 15) + j];
    out[j] = s;
}

extern "C" void kernel_launch(void* const* d_in, const int* in_sizes, int n_in,
                              void* d_out, int out_size, void* d_ws, size_t ws_size,
                              hipStream_t stream) {
    const float* x    = (const float*)d_in[0];
    const float* k    = (const float*)d_in[1];
    const float* Ec   = (const float*)d_in[2];
    const float* Ps   = (const float*)d_in[3];
    const float* bias = (const float*)d_in[4];
    const float* coef = (const float*)d_in[5];
    float* out = (float*)d_out;
    float* ws  = (float*)d_ws;

    const size_t repBytes = (size_t)32768 * sizeof(float);   // 128 KB per replica
    int R = 0;
    if (ws_size >= repBytes) {
        R = 1;
        while (R < 16 && (size_t)(R * 2) * repBytes <= ws_size) R <<= 1;
    }

    if (R >= 2) {
        hipMemsetAsync(ws, 0, (size_t)R * repBytes, stream);
        ferro_kernel<<<dim3(IN_DIM * 8), dim3(256), 0, stream>>>(
            x, k, Ec, Ps, bias, coef, ws, R - 1);
        reduce_kernel<<<dim3(128), dim3(256), 0, stream>>>(ws, out, R);
    } else {
        hipMemsetAsync(out, 0, (size_t)out_size * sizeof(float), stream);
        ferro_kernel<<<dim3(IN_DIM * 8), dim3(256), 0, stream>>>(
            x, k, Ec, Ps, bias, coef, out, 0);
    }
}